// Round 2
// baseline (522.672 us; speedup 1.0000x reference)
//
#include <hip/hip_runtime.h>
#include <hip/hip_bf16.h>
#include <stdint.h>

// Problem constants (QuantizedLinear_22849226015470)
#define MROWS 8192      // 4*2048 activation rows
#define K_TOT 4096      // in_features
#define N_TOT 4096      // out_features
// trellis: NB=65536 tiles (256 out-tiles x 256 in-tiles of 16x16), 32 x 16-bit
// words per tile; state_t = 16-bit big-endian window at bit 2t (circular 512).
//
// Identity used here: out = (x·(I⊗H))·Wˢᵀ = x·(Wˢ·(I⊗H))ᵀ  (H128 symmetric),
// and the per-(row,128-group) scale commutes with H within its group. So we
// rotate the decoded WEIGHTS via MFMA (H entries ±1, exact in bf16; 1/√128
// folded into the scale) and the activation path is a pure fp32→bf16 convert.

typedef __attribute__((ext_vector_type(8))) short bf16x8;
typedef __attribute__((ext_vector_type(4))) float f32x4;
typedef __attribute__((ext_vector_type(8))) unsigned short ushort8;

#define GLB(p) ((const __attribute__((address_space(1))) void*)(p))
#define LDSP(p) ((__attribute__((address_space(3))) void*)(p))

#define CONV_BLOCKS 16384  // 33.5M elems / (256 thr * 8 elems)
#define DEC_BLOCKS  2048   // 8192 strips (16 rows x 128 cols) / 4 per block

// ---------------- activation convert: fp32 -> bf16 (pure BW) ----------------
__global__ __launch_bounds__(256) void conv_k(const float* __restrict__ in,
                                              __hip_bfloat16* __restrict__ xb) {
    const int tid = threadIdx.x;
    const long base = ((long)blockIdx.x * 256 + tid) * 8;
    float4 x0 = *(const float4*)(in + base);
    float4 x1 = *(const float4*)(in + base + 4);
    ushort8 u;
    __hip_bfloat16 h;
    h = __float2bfloat16(x0.x); u[0] = *(unsigned short*)&h;
    h = __float2bfloat16(x0.y); u[1] = *(unsigned short*)&h;
    h = __float2bfloat16(x0.z); u[2] = *(unsigned short*)&h;
    h = __float2bfloat16(x0.w); u[3] = *(unsigned short*)&h;
    h = __float2bfloat16(x1.x); u[4] = *(unsigned short*)&h;
    h = __float2bfloat16(x1.y); u[5] = *(unsigned short*)&h;
    h = __float2bfloat16(x1.z); u[6] = *(unsigned short*)&h;
    h = __float2bfloat16(x1.w); u[7] = *(unsigned short*)&h;
    *(ushort8*)((unsigned short*)xb + base) = u;
}

// ---------------- trellis decode + H128 rotate ------------------------------
__global__ __launch_bounds__(256) void dec_k(const int* __restrict__ trellis,
                                             const float* __restrict__ tlut,
                                             const float* __restrict__ scales,
                                             __hip_bfloat16* __restrict__ wb) {
    __shared__ uint32_t sw[1024];                  // 32 tiles x 32 words
    __shared__ __hip_bfloat16 Hs[128 * 136];       // H[n][k], +8 pad
    const int tid = threadIdx.x;
    const int b = blockIdx.x;
    const int tbx = b >> 3;            // out-row tile (0..255)
    const int g0 = (b & 7) * 4;        // first 128-group of this block
    {
        int4 v = *((const int4*)(trellis + ((long)tbx * 256 + g0 * 8) * 32) + tid);
        sw[tid * 4 + 0] = (uint32_t)v.x & 0xFFFFu;
        sw[tid * 4 + 1] = (uint32_t)v.y & 0xFFFFu;
        sw[tid * 4 + 2] = (uint32_t)v.z & 0xFFFFu;
        sw[tid * 4 + 3] = (uint32_t)v.w & 0xFFFFu;
    }
    {
        const int n = tid >> 1;
        const int k0 = (tid & 1) * 64;
        const unsigned short pos = 0x3F80, neg = 0xBF80;
#pragma unroll 8
        for (int k = 0; k < 64; k++) {
            unsigned short s = (__popc(n & (k0 + k)) & 1) ? neg : pos;
            *((unsigned short*)Hs + n * 136 + k0 + k) = s;
        }
    }
    __syncthreads();

    const int wave = tid >> 6;         // strip within block
    const int lane = tid & 63;
    const int m = lane & 15;           // out-row within strip
    const int quad = lane >> 4;
    const int g = g0 + wave;           // 128-group index (0..31)

    bf16x8 af[4];
#pragma unroll
    for (int kc = 0; kc < 4; kc++) {
        float v[8];
#pragma unroll
        for (int j = 0; j < 8; j++) {
            const int k = kc * 32 + quad * 8 + j;   // col within strip
            const int tile = wave * 8 + (k >> 4);   // tile in LDS
            const int c = k & 15;                   // col within tile
            const int t = m * 16 + c;               // state index
            const int q = t >> 3;                   // word index
            const int rb = (c & 7) * 2;             // bit offset (even)
            const uint32_t w0 = sw[tile * 32 + q];
            const uint32_t w1 = sw[tile * 32 + ((q + 1) & 31)];
            const uint32_t st = ((w0 << rb) | (w1 >> (16 - rb))) & 0xFFFFu;
            v[j] = tlut[st];
        }
#pragma unroll
        for (int j = 0; j < 8; j++) {
            __hip_bfloat16 h = __float2bfloat16(v[j]);
            af[kc][j] = *(short*)&h;
        }
    }
    float scl[4];
#pragma unroll
    for (int r = 0; r < 4; r++)
        scl[r] = scales[(tbx * 16 + quad * 4 + r) * 32 + g] * 0.088388347648318447f;

#pragma unroll
    for (int nt = 0; nt < 8; nt++) {
        f32x4 c = {};
#pragma unroll
        for (int kc = 0; kc < 4; kc++) {
            bf16x8 bf = *(const bf16x8*)&Hs[(nt * 16 + m) * 136 + kc * 32 + quad * 8];
            c = __builtin_amdgcn_mfma_f32_16x16x32_bf16(af[kc], bf, c, 0, 0, 0);
        }
        const long col = (long)g * 128 + nt * 16 + m;   // C/D: col = lane&15
#pragma unroll
        for (int r = 0; r < 4; r++) {
            const long orow = tbx * 16 + quad * 4 + r;  // C/D: row = quad*4+reg
            wb[orow * K_TOT + col] = __float2bfloat16(c[r] * scl[r]);
        }
    }
}

// ---------------- bf16 GEMM: C[m,n] = sum_k A[m,k]*B[n,k]  (both K-contig) --
// 256x256 tile, 512 threads (8 waves, 2M x 4N). Ring of 4 K32-step slots
// (128 KiB LDS), staging always 2 steps ahead via global_load_lds width-16,
// counted s_waitcnt vmcnt(4) once per step (never 0 in main loop).
// Fine-phase schedule (T3+T5): each K32 step = 2 phases of 16 MFMA:
//   phase A: ds_read bfr[0..3]+afA[0..3] | stage A(s+2) | bar | MFMA iA | bar
//   phase B: ds_read afB[0..3] (bfr reused) | stage B(s+2) | bar | MFMA iB
//            | vmcnt(4) | bar
// LDS granule swizzle (T2): physical granule p holds logical
// (row=p>>2, seg=(p&3)^((row>>1)&3)); applied on the GLOBAL source address
// (LDS writes stay linear as global_load_lds requires) and on the ds_read
// address -> measured 0 bank conflicts.
#define BK 32
#define NSTEPS (K_TOT / BK)       // 128
#define SLOT_SZ 32768             // A 16KB + B 16KB per ring slot

__global__ __launch_bounds__(512, 2) void gemm_k(const __hip_bfloat16* __restrict__ A,
                                                 const __hip_bfloat16* __restrict__ B,
                                                 float* __restrict__ C) {
    __shared__ __align__(16) char sbuf[4 * SLOT_SZ];   // 128 KiB
    const int tid  = threadIdx.x;
    const int wave = tid >> 6;
    const int lane = tid & 63;

    // XCD-aware bijective chunk swizzle (512 blocks, 64 per XCD)
    const int bid  = (int)blockIdx.y * (N_TOT / 256) + (int)blockIdx.x;  // 0..511
    const int sbid = (bid & 7) * 64 + (bid >> 3);
    const long m0 = (long)(sbid >> 4) * 256;   // 0..31 m-tiles
    const long n0 = (long)(sbid & 15) * 256;   // 0..15 n-tiles

    // wave grid: 2 (M) x 4 (N); wave owns 128x64 of C
    const int wm = wave >> 2;          // 0..1
    const int wn = wave & 3;           // 0..3

    // ---- staging source pointers (per-thread, pre-swizzled global addr) ----
    const int p0 = tid, p1 = 512 + tid;
    const int r0 = p0 >> 2, r1 = p1 >> 2;
    const int sg0 = (p0 & 3) ^ ((r0 >> 1) & 3);
    const int sg1 = (p1 & 3) ^ ((r1 >> 1) & 3);
    const __hip_bfloat16* srcA0 = A + (m0 + r0) * K_TOT + sg0 * 8;
    const __hip_bfloat16* srcA1 = A + (m0 + r1) * K_TOT + sg1 * 8;
    const __hip_bfloat16* srcB0 = B + (n0 + r0) * K_TOT + sg0 * 8;
    const __hip_bfloat16* srcB1 = B + (n0 + r1) * K_TOT + sg1 * 8;
    // wave-uniform LDS dest byte offsets within an operand region
    const int ldsOff0 = wave * 1024;
    const int ldsOff1 = 8192 + wave * 1024;

    // ---- ds_read addressing (swizzled) ----
    const int lr  = lane & 15;
    const int lq  = lane >> 4;
    const int xsw = (lq ^ ((lr >> 1) & 3)) * 16;   // swizzled 16B granule off
    const int arow0 = wm * 128 + lr;               // + i*16
    const int brow0 = wn * 64 + lr;                // + j*16

    f32x4 acc[8][4] = {};

#define STAGE_A(ss)                                                                        \
    do {                                                                                   \
        char* _b = (char*)sbuf + ((ss) & 3) * SLOT_SZ;                                     \
        const long _ko = (long)(ss) * BK;                                                  \
        __builtin_amdgcn_global_load_lds(GLB(srcA0 + _ko), LDSP(_b + ldsOff0), 16, 0, 0);  \
        __builtin_amdgcn_global_load_lds(GLB(srcA1 + _ko), LDSP(_b + ldsOff1), 16, 0, 0);  \
    } while (0)
#define STAGE_B(ss)                                                                        \
    do {                                                                                   \
        char* _b = (char*)sbuf + ((ss) & 3) * SLOT_SZ + 16384;                             \
        const long _ko = (long)(ss) * BK;                                                  \
        __builtin_amdgcn_global_load_lds(GLB(srcB0 + _ko), LDSP(_b + ldsOff0), 16, 0, 0);  \
        __builtin_amdgcn_global_load_lds(GLB(srcB1 + _ko), LDSP(_b + ldsOff1), 16, 0, 0);  \
    } while (0)

    // prologue: steps 0,1 issued; wait step 0 landed (step 1's 4 in flight)
    STAGE_A(0); STAGE_B(0);
    STAGE_A(1); STAGE_B(1);
    asm volatile("s_waitcnt vmcnt(4)" ::: "memory");
    __builtin_amdgcn_s_barrier();
    asm volatile("" ::: "memory");

    for (int s = 0; s < NSTEPS; ++s) {
        const char* bufA = (const char*)sbuf + (s & 3) * SLOT_SZ;
        const char* bufB = bufA + 16384;

        // ---- phase A: bfr + low-half af, stage A(s+2) ----
        bf16x8 bfr[4], afA[4], afB[4];
#pragma unroll
        for (int j = 0; j < 4; j++)
            bfr[j] = *(const bf16x8*)(bufB + (brow0 + j * 16) * 64 + xsw);
#pragma unroll
        for (int i = 0; i < 4; i++)
            afA[i] = *(const bf16x8*)(bufA + (arow0 + i * 16) * 64 + xsw);
        if (s + 2 < NSTEPS) STAGE_A(s + 2);
        __builtin_amdgcn_s_barrier();
        asm volatile("" ::: "memory");

        __builtin_amdgcn_s_setprio(1);
#pragma unroll
        for (int i = 0; i < 4; i++)
#pragma unroll
            for (int j = 0; j < 4; j++)
                acc[i][j] = __builtin_amdgcn_mfma_f32_16x16x32_bf16(afA[i], bfr[j], acc[i][j], 0, 0, 0);
        __builtin_amdgcn_s_setprio(0);
        __builtin_amdgcn_s_barrier();
        asm volatile("" ::: "memory");

        // ---- phase B: high-half af (bfr reused), stage B(s+2) ----
#pragma unroll
        for (int i = 0; i < 4; i++)
            afB[i] = *(const bf16x8*)(bufA + (arow0 + (i + 4) * 16) * 64 + xsw);
        if (s + 2 < NSTEPS) STAGE_B(s + 2);
        __builtin_amdgcn_s_barrier();
        asm volatile("" ::: "memory");

        __builtin_amdgcn_s_setprio(1);
#pragma unroll
        for (int i = 0; i < 4; i++)
#pragma unroll
            for (int j = 0; j < 4; j++)
                acc[i + 4][j] = __builtin_amdgcn_mfma_f32_16x16x32_bf16(afB[i], bfr[j], acc[i + 4][j], 0, 0, 0);
        __builtin_amdgcn_s_setprio(0);

        if (s + 2 < NSTEPS)      asm volatile("s_waitcnt vmcnt(4)" ::: "memory");
        else if (s + 1 < NSTEPS) asm volatile("s_waitcnt vmcnt(0)" ::: "memory");
        if (s + 1 < NSTEPS) {
            __builtin_amdgcn_s_barrier();
            asm volatile("" ::: "memory");
        }
    }
#undef STAGE_A
#undef STAGE_B

    // epilogue: C/D layout col = lane&15, row = lq*4 + r
#pragma unroll
    for (int i = 0; i < 8; i++)
#pragma unroll
        for (int j = 0; j < 4; j++) {
            const long m = m0 + wm * 128 + i * 16 + lq * 4;
            const long n = n0 + wn * 64 + j * 16 + lr;
            float* cp = C + m * N_TOT + n;
#pragma unroll
            for (int r = 0; r < 4; r++)
                cp[(long)r * N_TOT] = acc[i][j][r];
        }
}

extern "C" void kernel_launch(void* const* d_in, const int* in_sizes, int n_in,
                              void* d_out, int out_size, void* d_ws, size_t ws_size,
                              hipStream_t stream) {
    const float* inp     = (const float*)d_in[0];   // (4,2048,4096) fp32
    const int*   trellis = (const int*)d_in[1];     // (65536,32) int32 (16-bit words)
    const float* tlut    = (const float*)d_in[2];   // (65536,1) fp32
    const float* scales  = (const float*)d_in[3];   // (131072,1) fp32
    float* out = (float*)d_out;                     // (4,2048,4096) fp32

    __hip_bfloat16* xb = (__hip_bfloat16*)d_ws;               // 64 MB
    __hip_bfloat16* wb = xb + (size_t)MROWS * K_TOT;          // 32 MB

    hipLaunchKernelGGL(conv_k, dim3(CONV_BLOCKS), dim3(256), 0, stream, inp, xb);
    hipLaunchKernelGGL(dec_k, dim3(DEC_BLOCKS), dim3(256), 0, stream, trellis, tlut, scales, wb);
    hipLaunchKernelGGL(gemm_k, dim3(N_TOT / 256, MROWS / 256), dim3(512), 0, stream, xb, wb, out);
}

// Round 3
// 489.953 us; speedup vs baseline: 1.0668x; 1.0668x over previous
//
#include <hip/hip_runtime.h>
#include <hip/hip_bf16.h>
#include <stdint.h>

// Problem constants (QuantizedLinear_22849226015470)
#define MROWS 8192      // 4*2048 activation rows
#define K_TOT 4096      // in_features
#define N_TOT 4096      // out_features
// trellis: NB=65536 tiles (256 out-tiles x 256 in-tiles of 16x16), 32 x 16-bit
// words per tile; state_t = 16-bit big-endian window at bit 2t (circular 512).
//
// Identity used here: out = (x·(I⊗H))·Wˢᵀ = x·(Wˢ·(I⊗H))ᵀ  (H128 symmetric),
// and the per-(row,128-group) scale commutes with H within its group. So we
// rotate the decoded WEIGHTS via MFMA (H entries ±1, exact in bf16; 1/√128
// folded into the scale) and the activation path is a pure fp32→bf16 convert.

typedef __attribute__((ext_vector_type(8))) short bf16x8;
typedef __attribute__((ext_vector_type(4))) float f32x4;
typedef __attribute__((ext_vector_type(8))) unsigned short ushort8;
typedef __attribute__((ext_vector_type(4))) unsigned short ushort4v;

#define GLB(p) ((const __attribute__((address_space(1))) void*)(p))
#define LDSP(p) ((__attribute__((address_space(3))) void*)(p))

#define CONV_BLOCKS 16384  // 33.5M elems / (256 thr * 8 elems)
#define DEC_BLOCKS  1024   // 8192 strips (16 rows x 128 cols) / 8 per block

// ---------------- activation convert: fp32 -> bf16 (pure BW) ----------------
__global__ __launch_bounds__(256) void conv_k(const float* __restrict__ in,
                                              __hip_bfloat16* __restrict__ xb) {
    const int tid = threadIdx.x;
    const long base = ((long)blockIdx.x * 256 + tid) * 8;
    float4 x0 = *(const float4*)(in + base);
    float4 x1 = *(const float4*)(in + base + 4);
    ushort8 u;
    __hip_bfloat16 h;
    h = __float2bfloat16(x0.x); u[0] = *(unsigned short*)&h;
    h = __float2bfloat16(x0.y); u[1] = *(unsigned short*)&h;
    h = __float2bfloat16(x0.z); u[2] = *(unsigned short*)&h;
    h = __float2bfloat16(x0.w); u[3] = *(unsigned short*)&h;
    h = __float2bfloat16(x1.x); u[4] = *(unsigned short*)&h;
    h = __float2bfloat16(x1.y); u[5] = *(unsigned short*)&h;
    h = __float2bfloat16(x1.z); u[6] = *(unsigned short*)&h;
    h = __float2bfloat16(x1.w); u[7] = *(unsigned short*)&h;
    *(ushort8*)((unsigned short*)xb + base) = u;
}

// ---------------- trellis decode + H128 rotate ------------------------------
// v2: the 2^16-entry LUT lives in LDS as bf16 (128 KB; bf16(tlut[st]) is
// bit-identical to the previous fp32-gather+convert). All 16.7M random
// gathers become ds_read_u16 instead of ~200-cy L2 round-trips. H entries
// (-1)^popc(n&k) are generated in-register (3 VALU/elem) -- no Hs LDS, so
// total LDS = 128K (tlut) + 8K (64 trellis tiles) = 136 KB, 1 block/CU.
// 512 threads = 8 waves = 8 strips (16 out-rows x 128 in-cols each).
__global__ __launch_bounds__(512) void dec_k(const int* __restrict__ trellis,
                                             const float* __restrict__ tlut,
                                             const float* __restrict__ scales,
                                             __hip_bfloat16* __restrict__ wb) {
    __shared__ unsigned short tl[65536];           // bf16 LUT, 128 KB
    __shared__ uint32_t sw[2048];                  // 64 tiles x 32 words
    const int tid = threadIdx.x;
    const int b = blockIdx.x;
    const int tbx = b >> 2;            // out-row tile (0..255)
    const int g0 = (b & 3) * 8;        // first 128-group of this block

    // ---- stage LUT: coalesced float4 reads (L2/L3-hot), pack to bf16 ----
#pragma unroll
    for (int it = 0; it < 32; ++it) {
        const int idx = it * 2048 + tid * 4;
        float4 f = *(const float4*)(tlut + idx);
        ushort4v u;
        __hip_bfloat16 h;
        h = __float2bfloat16(f.x); u[0] = *(unsigned short*)&h;
        h = __float2bfloat16(f.y); u[1] = *(unsigned short*)&h;
        h = __float2bfloat16(f.z); u[2] = *(unsigned short*)&h;
        h = __float2bfloat16(f.w); u[3] = *(unsigned short*)&h;
        *(ushort4v*)&tl[idx] = u;
    }
    // ---- stage trellis words: 64 consecutive tiles, one int4 per thread ----
    {
        int4 v = *((const int4*)(trellis + ((long)tbx * 256 + g0 * 8) * 32) + tid);
        sw[tid * 4 + 0] = (uint32_t)v.x & 0xFFFFu;
        sw[tid * 4 + 1] = (uint32_t)v.y & 0xFFFFu;
        sw[tid * 4 + 2] = (uint32_t)v.z & 0xFFFFu;
        sw[tid * 4 + 3] = (uint32_t)v.w & 0xFFFFu;
    }
    __syncthreads();

    const int wave = tid >> 6;         // strip within block (0..7)
    const int lane = tid & 63;
    const int m = lane & 15;           // out-row within strip
    const int quad = lane >> 4;
    const int g = g0 + wave;           // 128-group index (0..31)

    // decode A-fragments: af[kc] holds Wdec[m][kc*32 + quad*8 + j]
    bf16x8 af[4];
#pragma unroll
    for (int kc = 0; kc < 4; kc++) {
#pragma unroll
        for (int j = 0; j < 8; j++) {
            const int k = kc * 32 + quad * 8 + j;   // col within strip
            const int tile = wave * 8 + (k >> 4);   // tile in LDS
            const int c = k & 15;                   // col within tile
            const int t = m * 16 + c;               // state index
            const int q = t >> 3;                   // word index
            const int rb = (c & 7) * 2;             // bit offset (even)
            const uint32_t w0 = sw[tile * 32 + q];
            const uint32_t w1 = sw[tile * 32 + ((q + 1) & 31)];
            const uint32_t st = ((w0 << rb) | (w1 >> (16 - rb))) & 0xFFFFu;
            af[kc][j] = (short)tl[st];              // bf16 LUT hit in LDS
        }
    }
    // per-lane output-row scales (row = quad*4 + reg), 1/sqrt(128) folded
    float scl[4];
#pragma unroll
    for (int r = 0; r < 4; r++)
        scl[r] = scales[(tbx * 16 + quad * 4 + r) * 32 + g] * 0.088388347648318447f;

    // rotate: for each 16-col output tile, C = Wdec(16x128) · H-frags
#pragma unroll
    for (int nt = 0; nt < 8; nt++) {
        f32x4 c = {};
        const int n = nt * 16 + m;
#pragma unroll
        for (int kc = 0; kc < 4; kc++) {
            bf16x8 bf;
#pragma unroll
            for (int j = 0; j < 8; j++) {
                const int k = kc * 32 + quad * 8 + j;
                bf[j] = (short)((__popc(n & k) & 1) ? 0xBF80 : 0x3F80);
            }
            c = __builtin_amdgcn_mfma_f32_16x16x32_bf16(af[kc], bf, c, 0, 0, 0);
        }
        const long col = (long)g * 128 + nt * 16 + m;   // C/D: col = lane&15
#pragma unroll
        for (int r = 0; r < 4; r++) {
            const long orow = tbx * 16 + quad * 4 + r;  // C/D: row = quad*4+reg
            wb[orow * K_TOT + col] = __float2bfloat16(c[r] * scl[r]);
        }
    }
}

// ---------------- bf16 GEMM: C[m,n] = sum_k A[m,k]*B[n,k]  (both K-contig) --
// 256x256 tile, BK=32, 512 threads (8 waves, 2M x 4N), depth-2 counted-vmcnt
// pipeline over 4 LDS buffers (128 KiB total): iteration t issues tile t+2's
// global_load_lds, computes tile t, and waits s_waitcnt vmcnt(4) (never 0) at
// the single raw s_barrier per iteration. [round-1 verified: 248 us, 0 bank
// conflicts, MfmaUtil 49; the finer 2-phase split regressed to 263 -- keep.]
// LDS granule swizzle (T2, 64B rows): logical (row, kseg) stored at physical
// kseg ^ ((row>>1)&3). Applied on the GLOBAL source address (LDS writes stay
// linear as global_load_lds requires) and on the ds_read address.
#define BK 32
#define NTILES (K_TOT / BK)       // 128
#define BUFSZ 32768               // A 16KB + B 16KB per K-tile

__global__ __launch_bounds__(512, 2) void gemm_k(const __hip_bfloat16* __restrict__ A,
                                                 const __hip_bfloat16* __restrict__ B,
                                                 float* __restrict__ C) {
    __shared__ __align__(16) char sbuf[4 * BUFSZ];   // 128 KiB
    const int tid  = threadIdx.x;
    const int wave = tid >> 6;
    const int lane = tid & 63;
    const long m0 = (long)blockIdx.y * 256;
    const long n0 = (long)blockIdx.x * 256;

    // wave grid: 2 (M) x 4 (N); wave owns 128x64 of C
    const int wm = wave >> 2;          // 0..1
    const int wn = wave & 3;           // 0..3

    // ---- staging source pointers (per-thread, pre-swizzled global addr) ----
    const __hip_bfloat16* srcA[2];
    const __hip_bfloat16* srcB[2];
#pragma unroll
    for (int j = 0; j < 2; j++) {
        const int p   = j * 512 + tid;
        const int row = p >> 2;
        const int seg = (p & 3) ^ ((row >> 1) & 3);
        srcA[j] = A + (m0 + row) * K_TOT + seg * 8;
        srcB[j] = B + (n0 + row) * K_TOT + seg * 8;
    }
    const int ldsOff0 = wave * 1024;
    const int ldsOff1 = 8192 + wave * 1024;

    // ---- ds_read addressing (swizzled) ----
    const int lr  = lane & 15;
    const int lq  = lane >> 4;
    const int xsw = (lq ^ ((lr >> 1) & 3)) * 16;   // swizzled 16B granule off
    const int arow0 = wm * 128 + lr;               // + i*16
    const int brow0 = wn * 64 + lr;                // + j*16

    f32x4 acc[8][4] = {};

#define STAGE(tt)                                                                         \
    do {                                                                                  \
        char* _b = (char*)sbuf + ((tt) & 3) * BUFSZ;                                      \
        const long _ko = (long)(tt) * BK;                                                 \
        __builtin_amdgcn_global_load_lds(GLB(srcA[0] + _ko), LDSP(_b + ldsOff0), 16, 0, 0);\
        __builtin_amdgcn_global_load_lds(GLB(srcA[1] + _ko), LDSP(_b + ldsOff1), 16, 0, 0);\
        __builtin_amdgcn_global_load_lds(GLB(srcB[0] + _ko), LDSP(_b + 16384 + ldsOff0), 16, 0, 0);\
        __builtin_amdgcn_global_load_lds(GLB(srcB[1] + _ko), LDSP(_b + 16384 + ldsOff1), 16, 0, 0);\
    } while (0)

    // prologue: tiles 0,1 issued; wait tile 0 landed (tile 1's 4 stay in flight)
    STAGE(0);
    STAGE(1);
    asm volatile("s_waitcnt vmcnt(4)" ::: "memory");
    __builtin_amdgcn_s_barrier();
    asm volatile("" ::: "memory");

    for (int t = 0; t < NTILES; ++t) {
        if (t + 2 < NTILES) STAGE(t + 2);   // into buf[(t+2)&3]; last read iter t-2

        const char* bufA = (const char*)sbuf + (t & 3) * BUFSZ;
        const char* bufB = bufA + 16384;

        bf16x8 bfr[4], af[4];
#pragma unroll
        for (int j = 0; j < 4; j++)
            bfr[j] = *(const bf16x8*)(bufB + (brow0 + j * 16) * 64 + xsw);
#pragma unroll
        for (int i = 0; i < 4; i++)
            af[i] = *(const bf16x8*)(bufA + (arow0 + i * 16) * 64 + xsw);

        __builtin_amdgcn_s_setprio(1);
#pragma unroll
        for (int i = 0; i < 4; i++)
#pragma unroll
            for (int j = 0; j < 4; j++)
                acc[i][j] = __builtin_amdgcn_mfma_f32_16x16x32_bf16(af[i], bfr[j], acc[i][j], 0, 0, 0);
        __builtin_amdgcn_s_setprio(0);

#pragma unroll
        for (int i = 0; i < 4; i++)
            af[i] = *(const bf16x8*)(bufA + (arow0 + (i + 4) * 16) * 64 + xsw);

        __builtin_amdgcn_s_setprio(1);
#pragma unroll
        for (int i = 0; i < 4; i++)
#pragma unroll
            for (int j = 0; j < 4; j++)
                acc[i + 4][j] = __builtin_amdgcn_mfma_f32_16x16x32_bf16(af[i], bfr[j], acc[i + 4][j], 0, 0, 0);
        __builtin_amdgcn_s_setprio(0);

        if (t + 1 < NTILES) {
            // counted wait: newest 4 outstanding = tile t+2's -> tile t+1 landed
            if (t + 2 < NTILES) asm volatile("s_waitcnt vmcnt(4)" ::: "memory");
            else                asm volatile("s_waitcnt vmcnt(0)" ::: "memory");
            __builtin_amdgcn_s_barrier();
            asm volatile("" ::: "memory");
        }
    }
#undef STAGE

    // epilogue: C/D layout col = lane&15, row = lq*4 + r
#pragma unroll
    for (int i = 0; i < 8; i++)
#pragma unroll
        for (int j = 0; j < 4; j++) {
            const long m = m0 + wm * 128 + i * 16 + lq * 4;
            const long n = n0 + wn * 64 + j * 16 + lr;
            float* cp = C + m * N_TOT + n;
#pragma unroll
            for (int r = 0; r < 4; r++)
                cp[(long)r * N_TOT] = acc[i][j][r];
        }
}

extern "C" void kernel_launch(void* const* d_in, const int* in_sizes, int n_in,
                              void* d_out, int out_size, void* d_ws, size_t ws_size,
                              hipStream_t stream) {
    const float* inp     = (const float*)d_in[0];   // (4,2048,4096) fp32
    const int*   trellis = (const int*)d_in[1];     // (65536,32) int32 (16-bit words)
    const float* tlut    = (const float*)d_in[2];   // (65536,1) fp32
    const float* scales  = (const float*)d_in[3];   // (131072,1) fp32
    float* out = (float*)d_out;                     // (4,2048,4096) fp32

    __hip_bfloat16* xb = (__hip_bfloat16*)d_ws;               // 64 MB
    __hip_bfloat16* wb = xb + (size_t)MROWS * K_TOT;          // 32 MB

    hipLaunchKernelGGL(conv_k, dim3(CONV_BLOCKS), dim3(256), 0, stream, inp, xb);
    hipLaunchKernelGGL(dec_k, dim3(DEC_BLOCKS), dim3(512), 0, stream, trellis, tlut, scales, wb);
    hipLaunchKernelGGL(gemm_k, dim3(N_TOT / 256, MROWS / 256), dim3(512), 0, stream, xb, wb, out);
}